// Round 9
// baseline (282.051 us; speedup 1.0000x reference)
//
#include <hip/hip_runtime.h>

#define NNODES 100000
#define NEDGES 1600000
#define BSHIFT 7
#define NB 782            // buckets of 128 nodes: bucket = dst >> 7
#define CAP 2560          // padded per-bucket capacity (mean 2048, +11 sigma)
#define EBLOCKS 391       // edge-scatter blocks (4096 edges each)
#define GEMM_BLOCKS 1563  // (NNODES + 63) / 64

typedef _Float16 f16;
typedef _Float16 v4h __attribute__((ext_vector_type(4)));
typedef _Float16 v8h __attribute__((ext_vector_type(8)));
typedef float v4f __attribute__((ext_vector_type(4)));

// ---------------------------------------------------------------------------
// Init: bucket cursors (bcur[b] = b*CAP) + weight transpose/convert to f16.
// ---------------------------------------------------------------------------
__global__ __launch_bounds__(256) void init_k(int* __restrict__ bcur,
                                              const float* __restrict__ W1,
                                              f16* __restrict__ W1t,
                                              const float* __restrict__ W2,
                                              f16* __restrict__ W2t) {
    int t = blockIdx.x * 256 + threadIdx.x;
    if (t < NB) bcur[t] = t * CAP;
    int u = t - 1024;
    if (u >= 0) {
        if (u < 128 * 128) {
            int k = u >> 7, n = u & 127;
            W1t[n * 128 + k] = (f16)W1[k * 128 + n];
        } else if (u < 128 * 128 + 128 * 64) {
            int v = u - 128 * 128;
            int k = v >> 6, n = v & 63;
            W2t[n * 128 + k] = (f16)W2[k * 64 + n];
        }
    }
}

// ---------------------------------------------------------------------------
// Fused: edge scatter into bucket-padded ebuf (blocks 0..EBLOCKS-1) +
// layer-1 MFMA GEMM with inline fp32->f16 A conversion (remaining blocks).
// ebuf entry packed 4B: src | (dst&127)<<24  (src < 2^17).
// ---------------------------------------------------------------------------
__global__ __launch_bounds__(256) void scatter_gemm1(
    const int* __restrict__ src, const int* __restrict__ dst,
    int* __restrict__ bcur, int* __restrict__ ebuf,
    const float* __restrict__ feat, const f16* __restrict__ W1t,
    f16* __restrict__ z1) {
    constexpr int PITCH = 136;
    __shared__ __align__(16) char smem[128 * PITCH * 2];  // 34816 B
    int tid = threadIdx.x;

    if (blockIdx.x < EBLOCKS) {
        int* h = (int*)smem;
        int* base_s = ((int*)smem) + 1024;
        for (int i = tid; i < NB; i += 256) h[i] = 0;
        __syncthreads();
        int base = blockIdx.x * 4096;
        int d[16], sv[16];
        for (int k = 0; k < 16; k++) {
            int e = base + k * 256 + tid;
            if (e < NEDGES) {
                d[k] = dst[e];
                sv[k] = src[e];
                atomicAdd(&h[d[k] >> BSHIFT], 1);
            } else {
                d[k] = -1;
            }
        }
        __syncthreads();
        for (int i = tid; i < NB; i += 256) {
            int c = h[i];
            if (c) base_s[i] = atomicAdd(&bcur[i], c);
            h[i] = 0;
        }
        __syncthreads();
        for (int k = 0; k < 16; k++) {
            if (d[k] >= 0) {
                int b = d[k] >> BSHIFT;
                int slot = atomicAdd(&h[b], 1);
                ebuf[base_s[b] + slot] = sv[k] | ((d[k] & 127) << 24);
            }
        }
        return;
    }

    // ---- GEMM-1 branch: z1 = f16(feat) @ W1t^T ----
    f16* wlds = (f16*)smem;
    for (int c = tid; c < 128 * 16; c += 256) {
        int n = c >> 4;
        int kc = c & 15;
        *(v8h*)&wlds[n * PITCH + kc * 8] = *(const v8h*)&W1t[n * 128 + kc * 8];
    }
    __syncthreads();

    int wave = tid >> 6, lane = tid & 63, quad = lane >> 4, l16 = lane & 15;
    int m0 = (blockIdx.x - EBLOCKS) * 64 + wave * 16;
    if (m0 >= NNODES) return;  // NNODES % 16 == 0

    v8h a[4];
    const float* arow = feat + (long)(m0 + l16) * 128 + quad * 8;
#pragma unroll
    for (int kb = 0; kb < 4; kb++) {
        float4 f0 = *(const float4*)(arow + kb * 32);
        float4 f1 = *(const float4*)(arow + kb * 32 + 4);
        v8h t = {(f16)f0.x, (f16)f0.y, (f16)f0.z, (f16)f0.w,
                 (f16)f1.x, (f16)f1.y, (f16)f1.z, (f16)f1.w};
        a[kb] = t;
    }

#pragma unroll
    for (int nt = 0; nt < 8; nt++) {
        v4f acc = {0.f, 0.f, 0.f, 0.f};
        const f16* brow = &wlds[(nt * 16 + l16) * PITCH + quad * 8];
#pragma unroll
        for (int kb = 0; kb < 4; kb++) {
            v8h b = *(const v8h*)(brow + kb * 32);
            acc = __builtin_amdgcn_mfma_f32_16x16x32_f16(a[kb], b, acc, 0, 0, 0);
        }
        int n = nt * 16 + l16;
#pragma unroll
        for (int r = 0; r < 4; r++)
            z1[(long)(m0 + quad * 4 + r) * 128 + n] = (f16)acc[r];
    }
}

// ---------------------------------------------------------------------------
// Per-bucket CSR fill (padded layout): count 128 nodes in LDS, scan, write
// begs/ends, place edges via LDS cursors. All writes in a ~10KB window.
// ---------------------------------------------------------------------------
__global__ __launch_bounds__(256) void fill_bucket(const int* __restrict__ ebuf,
                                                   const int* __restrict__ bcur,
                                                   int* __restrict__ begs,
                                                   int* __restrict__ ends,
                                                   int* __restrict__ csr) {
    __shared__ int lc[128];
    __shared__ int ls[256];
    int b = blockIdx.x;
    int tid = threadIdx.x;
    if (tid < 128) lc[tid] = 0;
    __syncthreads();
    int ebeg = b * CAP;
    int eend = bcur[b];  // = b*CAP + bucket count
    for (int e = ebeg + tid; e < eend; e += 256)
        atomicAdd(&lc[((unsigned)ebuf[e]) >> 24], 1);
    __syncthreads();
    int cnt = (tid < 128) ? lc[tid] : 0;
    ls[tid] = cnt;
    __syncthreads();
    for (int off = 1; off < 256; off <<= 1) {
        int t = (tid >= off) ? ls[tid - off] : 0;
        __syncthreads();
        ls[tid] += t;
        __syncthreads();
    }
    int excl = ls[tid] - cnt;
    int node = (b << BSHIFT) + tid;
    if (tid < 128 && node < NNODES) {
        begs[node] = ebeg + excl;
        ends[node] = ebeg + excl + cnt;
    }
    if (tid < 128) { ls[tid] = excl; lc[tid] = 0; }
    __syncthreads();
    for (int e = ebeg + tid; e < eend; e += 256) {
        int p = ebuf[e];
        int dloc = ((unsigned)p) >> 24;
        int slot = atomicAdd(&lc[dloc], 1);
        csr[ebeg + ls[dloc] + slot] = p & 0xFFFFFF;
    }
}

// ---------------------------------------------------------------------------
// Fused layer-1 gather + layer-2 projection, 256-thread blocks = 4 waves =
// 4 nodes (decouples the epilogue barrier from degree variance; 25000 blocks
// give the scheduler freedom). Each wave gathers its node's z1 rows
// (half-waves own edges, 16 edges/iter, packed-f16 tree reduce, fp32 master
// acc), computes h1 = relu((sum+self)/(deg+1)+b1) into an LDS tile (rows
// 4..15 zeroed); a 4-wave MFMA epilogue computes z2 = h1 @ W2t^T directly.
// ---------------------------------------------------------------------------
__global__ __launch_bounds__(256) void gather128_gemm2(
    const v4h* __restrict__ z,        // z1, rows of 32 v4h
    const int* __restrict__ begs, const int* __restrict__ ends,
    const int* __restrict__ csr,
    const float* __restrict__ b1,     // [128]
    const f16* __restrict__ W2t,      // [64,128]
    f16* __restrict__ z2)             // [NNODES,64]
{
    constexpr int PITCH = 136;
    __shared__ f16 w2lds[64 * PITCH];   // 17408 B
    __shared__ f16 atile[16 * PITCH];   //  4352 B
    int tid = threadIdx.x;

    // stage W2t (1024 chunks of 8 halves) + zero atile (272 chunks)
    for (int t = tid; t < 1024; t += 256) {
        int n = t >> 4, kc = t & 15;
        *(v8h*)&w2lds[n * PITCH + kc * 8] = *(const v8h*)&W2t[n * 128 + kc * 8];
    }
    {
        v8h zz = {0, 0, 0, 0, 0, 0, 0, 0};
        for (int t = tid; t < 272; t += 256) *(v8h*)&atile[t * 8] = zz;
    }
    __syncthreads();

    int wavei = tid >> 6;  // local node 0..3
    int lane = tid & 63;
    int half = lane >> 5;
    int c = lane & 31;
    int node = blockIdx.x * 4 + wavei;  // 25000*4 == NNODES exactly

    int beg = begs[node];
    int end = ends[node];

    v4h svv = {0, 0, 0, 0};
    if (half == 0) svv = z[(long)node * 32 + c];  // self term

    float a0 = 0.f, a1 = 0.f, a2 = 0.f, a3 = 0.f;

    int e = beg;
    for (; e + 15 < end; e += 16) {
        int i0 = csr[e + half];
        int i1 = csr[e + 2 + half];
        int i2 = csr[e + 4 + half];
        int i3 = csr[e + 6 + half];
        int i4 = csr[e + 8 + half];
        int i5 = csr[e + 10 + half];
        int i6 = csr[e + 12 + half];
        int i7 = csr[e + 14 + half];
        v4h u0 = z[(long)i0 * 32 + c];
        v4h u1 = z[(long)i1 * 32 + c];
        v4h u2 = z[(long)i2 * 32 + c];
        v4h u3 = z[(long)i3 * 32 + c];
        v4h u4 = z[(long)i4 * 32 + c];
        v4h u5 = z[(long)i5 * 32 + c];
        v4h u6 = z[(long)i6 * 32 + c];
        v4h u7 = z[(long)i7 * 32 + c];
        v4h s01 = u0 + u1, s23 = u2 + u3, s45 = u4 + u5, s67 = u6 + u7;
        v4h s03 = s01 + s23, s47 = s45 + s67;
        v4h s = s03 + s47;
        a0 += (float)s[0]; a1 += (float)s[1];
        a2 += (float)s[2]; a3 += (float)s[3];
    }
    for (; e + 3 < end; e += 4) {
        int i0 = csr[e + half];
        int i1 = csr[e + 2 + half];
        v4h u0 = z[(long)i0 * 32 + c];
        v4h u1 = z[(long)i1 * 32 + c];
        v4h s = u0 + u1;
        a0 += (float)s[0]; a1 += (float)s[1];
        a2 += (float)s[2]; a3 += (float)s[3];
    }
    for (; e < end; e += 2) {
        int t = e + half;
        if (t < end) {
            v4h u = z[(long)csr[t] * 32 + c];
            a0 += (float)u[0]; a1 += (float)u[1];
            a2 += (float)u[2]; a3 += (float)u[3];
        }
    }
    a0 += (float)svv[0]; a1 += (float)svv[1];
    a2 += (float)svv[2]; a3 += (float)svv[3];

    a0 += __shfl_xor(a0, 32);
    a1 += __shfl_xor(a1, 32);
    a2 += __shfl_xor(a2, 32);
    a3 += __shfl_xor(a3, 32);

    if (half == 0) {
        float inv = 1.0f / (float)(end - beg + 1);
        float4 bb = ((const float4*)b1)[c];
        v4h o = {(f16)fmaxf(a0 * inv + bb.x, 0.f),
                 (f16)fmaxf(a1 * inv + bb.y, 0.f),
                 (f16)fmaxf(a2 * inv + bb.z, 0.f),
                 (f16)fmaxf(a3 * inv + bb.w, 0.f)};
        *(v4h*)&atile[wavei * PITCH + c * 4] = o;
    }
    __syncthreads();

    // ---- epilogue: z2[4 rows] = atile(4 valid rows) @ W2t^T.
    // All 4 waves run one 16x16 n-tile each (n = wavei*16 + l16); only
    // quad 0 (D rows 0..3) holds valid output rows.
    {
        int quad = lane >> 4, l16 = lane & 15;
        const f16* arow = &atile[l16 * PITCH + quad * 8];
        const f16* brow = &w2lds[(wavei * 16 + l16) * PITCH + quad * 8];
        v4f acc = {0.f, 0.f, 0.f, 0.f};
#pragma unroll
        for (int kb = 0; kb < 4; kb++) {
            v8h av = *(const v8h*)(arow + kb * 32);
            v8h bv = *(const v8h*)(brow + kb * 32);
            acc = __builtin_amdgcn_mfma_f32_16x16x32_f16(av, bv, acc, 0, 0, 0);
        }
        if (quad == 0) {
            int n = wavei * 16 + l16;
            int m0 = blockIdx.x * 4;
#pragma unroll
            for (int r = 0; r < 4; r++)
                z2[(long)(m0 + r) * 64 + n] = (f16)acc[r];
        }
    }
}

// ---------------------------------------------------------------------------
// Layer-2 gather+normalize over 64-wide f16 rows, fp32 out:
//   out[n] = (Σ z2[src] + z2[n]) / (deg+1) + b2
// 16-lane subgroups; 32 edges/iter = 8 loads in flight; f16 tree reduction.
// ---------------------------------------------------------------------------
__global__ void gather64(const v4h* __restrict__ z, const int* __restrict__ begs,
                         const int* __restrict__ ends, const int* __restrict__ csr,
                         const float* __restrict__ bias, float4* __restrict__ out) {
    int node = (int)(((long)blockIdx.x * blockDim.x + threadIdx.x) >> 6);
    if (node >= NNODES) return;
    int lane = threadIdx.x & 63;
    int sub = lane >> 4;
    int c = lane & 15;

    int beg = begs[node];
    int end = ends[node];

    v4h svv = {0, 0, 0, 0};
    if (sub == 0) svv = z[(long)node * 16 + c];

    float a0 = 0.f, a1 = 0.f, a2 = 0.f, a3 = 0.f;

    int e = beg;
    for (; e + 31 < end; e += 32) {
        int i0 = csr[e + sub];
        int i1 = csr[e + 4 + sub];
        int i2 = csr[e + 8 + sub];
        int i3 = csr[e + 12 + sub];
        int i4 = csr[e + 16 + sub];
        int i5 = csr[e + 20 + sub];
        int i6 = csr[e + 24 + sub];
        int i7 = csr[e + 28 + sub];
        v4h u0 = z[(long)i0 * 16 + c];
        v4h u1 = z[(long)i1 * 16 + c];
        v4h u2 = z[(long)i2 * 16 + c];
        v4h u3 = z[(long)i3 * 16 + c];
        v4h u4 = z[(long)i4 * 16 + c];
        v4h u5 = z[(long)i5 * 16 + c];
        v4h u6 = z[(long)i6 * 16 + c];
        v4h u7 = z[(long)i7 * 16 + c];
        v4h s01 = u0 + u1, s23 = u2 + u3, s45 = u4 + u5, s67 = u6 + u7;
        v4h s03 = s01 + s23, s47 = s45 + s67;
        v4h s = s03 + s47;
        a0 += (float)s[0]; a1 += (float)s[1];
        a2 += (float)s[2]; a3 += (float)s[3];
    }
    for (; e + 7 < end; e += 8) {
        int i0 = csr[e + sub];
        int i1 = csr[e + 4 + sub];
        v4h u0 = z[(long)i0 * 16 + c];
        v4h u1 = z[(long)i1 * 16 + c];
        v4h s = u0 + u1;
        a0 += (float)s[0]; a1 += (float)s[1];
        a2 += (float)s[2]; a3 += (float)s[3];
    }
    for (; e < end; e += 4) {
        int t = e + sub;
        if (t < end) {
            v4h u = z[(long)csr[t] * 16 + c];
            a0 += (float)u[0]; a1 += (float)u[1];
            a2 += (float)u[2]; a3 += (float)u[3];
        }
    }
    a0 += (float)svv[0]; a1 += (float)svv[1];
    a2 += (float)svv[2]; a3 += (float)svv[3];

    a0 += __shfl_xor(a0, 16);  a0 += __shfl_xor(a0, 32);
    a1 += __shfl_xor(a1, 16);  a1 += __shfl_xor(a1, 32);
    a2 += __shfl_xor(a2, 16);  a2 += __shfl_xor(a2, 32);
    a3 += __shfl_xor(a3, 16);  a3 += __shfl_xor(a3, 32);

    if (sub == 0) {
        float inv = 1.0f / (float)(end - beg + 1);
        float4 b = ((const float4*)bias)[c];
        out[(long)node * 16 + c] =
            make_float4(a0 * inv + b.x, a1 * inv + b.y, a2 * inv + b.z, a3 * inv + b.w);
    }
}

extern "C" void kernel_launch(void* const* d_in, const int* in_sizes, int n_in,
                              void* d_out, int out_size, void* d_ws, size_t ws_size,
                              hipStream_t stream) {
    const float* feat = (const float*)d_in[0];
    const float* W1   = (const float*)d_in[1];
    const float* b1   = (const float*)d_in[2];
    const float* W2   = (const float*)d_in[3];
    const float* b2   = (const float*)d_in[4];
    const int*   src  = (const int*)d_in[5];
    const int*   dst  = (const int*)d_in[6];
    float* out = (float*)d_out;

    // Workspace layout:
    //   bcur i32[782]       @ 0x0000000
    //   begs i32[100000]    @ 0x0001000  (400000 B)
    //   ends i32[100000]    @ 0x0063000  (400000 B)
    //   csr  i32[NB*CAP=2001920] @ 0x00C5000  (8.0 MB, bucket-padded)
    //   ebuf i32[NB*CAP]    @ 0x0870000  (8.0 MB, bucket-padded)
    //   z1   f16[12.8M]     @ 0x1100000  (25.6 MB)
    //   z2   f16[6.4M]      @ 0x2A00000  (12.8 MB)
    //   W1t  f16[16384]     @ 0x3700000
    //   W2t  f16[8192]      @ 0x3710000
    char* ws = (char*)d_ws;
    int* bcur = (int*)(ws + 0x0000000);
    int* begs = (int*)(ws + 0x0001000);
    int* ends = (int*)(ws + 0x0063000);
    int* csr  = (int*)(ws + 0x00C5000);
    int* ebuf = (int*)(ws + 0x0870000);
    f16* z1   = (f16*)(ws + 0x1100000);
    f16* z2   = (f16*)(ws + 0x2A00000);
    f16* W1t  = (f16*)(ws + 0x3700000);
    f16* W2t  = (f16*)(ws + 0x3710000);

    // 1. init cursors + weight prep
    init_k<<<100, 256, 0, stream>>>(bcur, W1, W1t, W2, W2t);

    // 2. edge scatter into padded buckets + layer-1 GEMM (fused)
    scatter_gemm1<<<EBLOCKS + GEMM_BLOCKS, 256, 0, stream>>>(src, dst, bcur, ebuf,
                                                             feat, W1t, z1);

    // 3. per-bucket CSR fill + per-node beg/end
    fill_bucket<<<NB, 256, 0, stream>>>(ebuf, bcur, begs, ends, csr);

    // 4. layer-1 gather (+bias+relu) fused with layer-2 projection
    gather128_gemm2<<<NNODES / 4, 256, 0, stream>>>((const v4h*)z1, begs, ends,
                                                    csr, b1, W2t, z2);

    // 5. layer-2 gather (+bias) -> output
    gather64<<<(NNODES * 64 + 255) / 256, 256, 0, stream>>>((const v4h*)z2, begs,
                                                            ends, csr, b2,
                                                            (float4*)out);
}